// Round 7
// baseline (531.768 us; speedup 1.0000x reference)
//
#include <hip/hip_runtime.h>

#define BATCH 2048

typedef unsigned short u16;
typedef __attribute__((ext_vector_type(8))) short bf16x8;  // 8 bf16 = 4 VGPR
typedef __attribute__((ext_vector_type(4))) float f32x4;   // MFMA 16x16 acc

static __device__ __forceinline__ float b2f(u16 h) {
  union { unsigned u; float f; } x; x.u = ((unsigned)h) << 16; return x.f;
}
static __device__ __forceinline__ u16 f2b(float f) {  // RNE fp32->bf16
  union { float f; unsigned u; } x; x.f = f;
  return (u16)((x.u + 0x7fffu + ((x.u >> 16) & 1u)) >> 16);
}
static __device__ __forceinline__ void split2(float v, u16& h, u16& l) {
  h = f2b(v); l = f2b(v - b2f(h));
}
// 8 bf16 from LDS at 8B alignment (2x ds_read_b64)
static __device__ __forceinline__ bf16x8 ld8u(const u16* p, int idx) {
  union { bf16x8 v; ushort4 u[2]; } x;
  x.u[0] = *(const ushort4*)(p + idx);
  x.u[1] = *(const ushort4*)(p + idx + 4);
  return x.v;
}

// ---------------------------------------------------------------------------
// Pre-split conv weights into direct-conv position-major layouts (hi plane
// then lo plane):
//   W1d [8 ky][32 oc][32 k]  k = kx*3+c for k<24, zeros k>=24  (8192 + 8192)
//   W2d [16 pos][64 oc][32 cc]                                (32768 + 32768)
//   W3d [9 pos][2 kc][64 oc][32 j]  cc = kc*32+j              (36864 + 36864)
// ---------------------------------------------------------------------------
__global__ void wsplit_kernel(const float* __restrict__ k1,
                              const float* __restrict__ k2,
                              const float* __restrict__ k3,
                              u16* __restrict__ W1d, u16* __restrict__ W2d,
                              u16* __restrict__ W3d)
{
  int id = blockIdx.x * 256 + threadIdx.x;   // 0..77823
  float v; u16 *dh, *dl;
  if (id < 8192) {
    int ky = id >> 10, oc = (id >> 5) & 31, kk = id & 31;
    if (kk < 24) {
      int kx = kk / 3, c = kk - kx * 3;
      v = k1[oc * 192 + c * 64 + ky * 8 + kx];
    } else v = 0.f;
    dh = W1d + id; dl = W1d + 8192 + id;
  } else if (id < 40960) {
    int i = id - 8192;
    int pos = i >> 11, oc = (i >> 5) & 63, cc = i & 31;
    int ky = pos >> 2, kx = pos & 3;
    v = k2[oc * 512 + cc * 16 + ky * 4 + kx];
    dh = W2d + i; dl = W2d + 32768 + i;
  } else {
    int i = id - 40960;                      // ((pos*2+kc)*64+oc)*32 + j
    int j = i & 31, oc = (i >> 5) & 63, kc = (i >> 11) & 1, pos = i >> 12;
    int ky = pos / 3, kx = pos - ky * 3;
    v = k3[oc * 576 + (kc * 32 + j) * 9 + ky * 3 + kx];
    dh = W3d + i; dl = W3d + 36864 + i;
  }
  u16 h, l; split2(v, h, l); *dh = h; *dl = l;
}

// ---------------------------------------------------------------------------
// Pre-split W1 [8][3136][64] fp32 -> W1s hi/lo bf16, B-frag layout
// [e][chunk][c(64)][kk(32)]. One block per (e,chunk) = 784 blocks x 256 thr.
// Reads stride-64 floats (L2-hot), writes 16B-contiguous ushort4 pairs —
// fully coalesced (the old version did 2B scattered stores at stride 64B,
// ~1/32 sector efficiency -> was the hidden ~200us).
// ---------------------------------------------------------------------------
__global__ void w1split_kernel(const float* __restrict__ W1,
                               u16* __restrict__ W1s)
{
  const int bc = blockIdx.x;                 // e*98 + chunk
  const int e = bc / 98, chunk = bc - e * 98;
  const int t = threadIdx.x;
  const float* in = W1 + (size_t)e * 200704 + chunk * 2048;
  const int c = t >> 2, kk0 = (t & 3) * 8;
  u16 h[8], l[8];
  #pragma unroll
  for (int j = 0; j < 8; ++j) {
    float v = in[(kk0 + j) * 64 + c];
    split2(v, h[j], l[j]);
  }
  ushort4 h0; h0.x = h[0]; h0.y = h[1]; h0.z = h[2]; h0.w = h[3];
  ushort4 h1; h1.x = h[4]; h1.y = h[5]; h1.z = h[6]; h1.w = h[7];
  ushort4 l0; l0.x = l[0]; l0.y = l[1]; l0.z = l[2]; l0.w = l[3];
  ushort4 l1; l1.x = l[4]; l1.y = l[5]; l1.z = l[6]; l1.w = l[7];
  size_t d = (size_t)e * 200704 + chunk * 2048 + t * 8;   // = c*32 + kk0
  *(ushort4*)(W1s + d)     = h0;
  *(ushort4*)(W1s + d + 4) = h1;
  *(ushort4*)(W1s + 1605632 + d)     = l0;
  *(ushort4*)(W1s + 1605632 + d + 4) = l1;
}

// ---------------------------------------------------------------------------
// Fused conv1+conv2+conv3, one block per image, 512 thr = 8 waves.
// (verified round-5/6 structure; conv3 writes a3 pre-split hi/lo)
// ---------------------------------------------------------------------------
__global__ __launch_bounds__(512, 4) void conv_fused_kernel(
    const float* __restrict__ state, const u16* __restrict__ W1d,
    const u16* __restrict__ W2d, const u16* __restrict__ W3d,
    const float* __restrict__ c1, const float* __restrict__ c2,
    const float* __restrict__ c3, u16* __restrict__ a3h,
    u16* __restrict__ a3l)
{
  __shared__ __align__(16) u16 A1h[14400], A1l[14400];  // [400][36]
  __shared__ __align__(16) u16 SHa[5832], SHb[5832];    // il [20][252] / a2 [81][72]

  const int b = blockIdx.x, t = threadIdx.x;
  const int lane = t & 63, w = t >> 6, q = lane >> 4, n = lane & 15;

  // Zero the il tail: conv1's zero-weight pad lanes read past the il band.
  for (int i = t; i < 792; i += 512) { SHa[5040 + i] = 0; SHb[5040 + i] = 0; }

  // ================= conv1: 84x84x3 -> 20x20x32, 8x8 s4, 5 bands =========
  const int nT1 = (w < 2) ? 2 : 1;
  int pt1[2], ot1[2];
  if (w < 2) { pt1[0] = 0; ot1[0] = w; pt1[1] = 4; ot1[1] = w; }
  else       { pt1[0] = 1 + ((w - 2) >> 1); ot1[0] = (w - 2) & 1;
               pt1[1] = pt1[0]; ot1[1] = ot1[0]; }

  int aoff1[2];
  #pragma unroll
  for (int i = 0; i < 2; ++i) {
    int px = pt1[i] * 16 + n;                 // <= 79
    int py = (px * 205) >> 12, pxx = px - py * 20;
    aoff1[i] = (py * 4) * 252 + pxx * 12 + q * 8;
  }
  float c1v[2];
  #pragma unroll
  for (int j = 0; j < 2; ++j) c1v[j] = c1[ot1[j] * 16 + n];
  const int ob1 = (ot1[0] * 16 + n) * 32 + q * 8;   // + ky*1024

  for (int by = 0; by < 5; ++by) {
    __syncthreads();
    const float4* sp = (const float4*)(state + (size_t)b * 21168 + by * 4032);
    #pragma unroll
    for (int pass = 0; pass < 3; ++pass) {
      int i = t + pass * 512;
      if (i < 1260) {
        float4 v = sp[i];
        u16 h0, l0, h1, l1, h2, l2, h3, l3;
        split2(v.x, h0, l0); split2(v.y, h1, l1);
        split2(v.z, h2, l2); split2(v.w, h3, l3);
        ushort4 hh; hh.x = h0; hh.y = h1; hh.z = h2; hh.w = h3;
        ushort4 ll; ll.x = l0; ll.y = l1; ll.z = l2; ll.w = l3;
        *(ushort4*)&SHa[i * 4] = hh;
        *(ushort4*)&SHb[i * 4] = ll;
      }
    }
    __syncthreads();

    f32x4 acc1[2] = {};
    bf16x8 bhc = *(const bf16x8*)(W1d + ob1);
    bf16x8 boc = *(const bf16x8*)(W1d + 8192 + ob1);
    for (int ky = 0; ky < 8; ++ky) {
      const int kyn = (ky < 7) ? ky + 1 : 7;
      bf16x8 bhn = *(const bf16x8*)(W1d + kyn * 1024 + ob1);
      bf16x8 bon = *(const bf16x8*)(W1d + 8192 + kyn * 1024 + ob1);
      #pragma unroll
      for (int i = 0; i < 2; ++i) if (i < nT1) {
        bf16x8 ah = ld8u(SHa, aoff1[i] + ky * 252);
        bf16x8 al = ld8u(SHb, aoff1[i] + ky * 252);
        acc1[i] = __builtin_amdgcn_mfma_f32_16x16x32_bf16(ah, bhc, acc1[i], 0, 0, 0);
        acc1[i] = __builtin_amdgcn_mfma_f32_16x16x32_bf16(ah, boc, acc1[i], 0, 0, 0);
        acc1[i] = __builtin_amdgcn_mfma_f32_16x16x32_bf16(al, bhc, acc1[i], 0, 0, 0);
      }
      bhc = bhn; boc = bon;
    }
    #pragma unroll
    for (int i = 0; i < 2; ++i) if (i < nT1) {
      int oc = ot1[i] * 16 + n;
      #pragma unroll
      for (int r = 0; r < 4; ++r) {
        int px = by * 80 + pt1[i] * 16 + q * 4 + r;
        float v = fmaxf(acc1[i][r] + c1v[i], 0.f);
        u16 h, l; split2(v, h, l);
        A1h[px * 36 + oc] = h; A1l[px * 36 + oc] = l;
      }
    }
  }
  __syncthreads();

  // ================= conv2: 20x20x32 -> 9x9x64, 4x4 s2 ===================
  {
    const int ot2 = w & 3, pg2 = (w >> 2) * 3;
    int aoff2[3];
    #pragma unroll
    for (int i = 0; i < 3; ++i) {
      int px = (pg2 + i) * 16 + n; if (px > 80) px = 80;
      int py = (px * 7282) >> 16, pxx = px - py * 9;
      aoff2[i] = 2 * (py * 20 + pxx) * 36 + q * 8;
    }
    const float c2v = c2[ot2 * 16 + n];
    const int ob2 = (ot2 * 16 + n) * 32 + q * 8;

    f32x4 acc2[3] = {};
    bf16x8 bhc = *(const bf16x8*)(W2d + ob2);
    bf16x8 boc = *(const bf16x8*)(W2d + 32768 + ob2);
    for (int pos = 0; pos < 16; ++pos) {
      const int posn = (pos < 15) ? pos + 1 : 15;
      bf16x8 bhn = *(const bf16x8*)(W2d + posn * 2048 + ob2);
      bf16x8 bon = *(const bf16x8*)(W2d + 32768 + posn * 2048 + ob2);
      const int o = ((pos >> 2) * 20 + (pos & 3)) * 36;
      #pragma unroll
      for (int i = 0; i < 3; ++i) {
        bf16x8 ah = ld8u(A1h, aoff2[i] + o);
        bf16x8 al = ld8u(A1l, aoff2[i] + o);
        acc2[i] = __builtin_amdgcn_mfma_f32_16x16x32_bf16(ah, bhc, acc2[i], 0, 0, 0);
        acc2[i] = __builtin_amdgcn_mfma_f32_16x16x32_bf16(ah, boc, acc2[i], 0, 0, 0);
        acc2[i] = __builtin_amdgcn_mfma_f32_16x16x32_bf16(al, bhc, acc2[i], 0, 0, 0);
      }
      bhc = bhn; boc = bon;
    }
    #pragma unroll
    for (int i = 0; i < 3; ++i) {
      int oc = ot2 * 16 + n;
      #pragma unroll
      for (int r = 0; r < 4; ++r) {
        int px = (pg2 + i) * 16 + q * 4 + r;
        if (px < 81) {
          float v = fmaxf(acc2[i][r] + c2v, 0.f);
          u16 h, l; split2(v, h, l);
          SHa[px * 72 + oc] = h; SHb[px * 72 + oc] = l;
        }
      }
    }
  }
  __syncthreads();

  // ================= conv3: 9x9x64 -> 7x7x64, 3x3 s1 =====================
  {
    const int ot3 = w & 3, pg3 = (w >> 2) * 2;
    int aoff3[2];
    #pragma unroll
    for (int i = 0; i < 2; ++i) {
      int px = (pg3 + i) * 16 + n; if (px > 48) px = 48;
      int py = (px * 74) >> 9, pxx = px - py * 7;
      aoff3[i] = (py * 9 + pxx) * 72 + q * 8;
    }
    const float c3v = c3[ot3 * 16 + n];
    const int ob3 = (ot3 * 16 + n) * 32 + q * 8;

    f32x4 acc3[2] = {};
    bf16x8 bhc = *(const bf16x8*)(W3d + ob3);
    bf16x8 boc = *(const bf16x8*)(W3d + 36864 + ob3);
    for (int pk = 0; pk < 18; ++pk) {           // pk = pos*2 + kc
      const int pkn = (pk < 17) ? pk + 1 : 17;
      bf16x8 bhn = *(const bf16x8*)(W3d + pkn * 2048 + ob3);
      bf16x8 bon = *(const bf16x8*)(W3d + 36864 + pkn * 2048 + ob3);
      const int pos = pk >> 1, kc = pk & 1;
      const int ky = pos / 3, kx = pos - ky * 3;
      const int o = (ky * 9 + kx) * 72 + kc * 32;
      #pragma unroll
      for (int i = 0; i < 2; ++i) {
        bf16x8 ah = *(const bf16x8*)&SHa[aoff3[i] + o];  // 16B aligned
        bf16x8 al = *(const bf16x8*)&SHb[aoff3[i] + o];
        acc3[i] = __builtin_amdgcn_mfma_f32_16x16x32_bf16(ah, bhc, acc3[i], 0, 0, 0);
        acc3[i] = __builtin_amdgcn_mfma_f32_16x16x32_bf16(ah, boc, acc3[i], 0, 0, 0);
        acc3[i] = __builtin_amdgcn_mfma_f32_16x16x32_bf16(al, bhc, acc3[i], 0, 0, 0);
      }
      bhc = bhn; boc = bon;
    }
    u16* oph = a3h + (size_t)b * 3136;
    u16* opl = a3l + (size_t)b * 3136;
    #pragma unroll
    for (int i = 0; i < 2; ++i) {
      int oc = ot3 * 16 + n;
      #pragma unroll
      for (int r = 0; r < 4; ++r) {
        int px = (pg3 + i) * 16 + q * 4 + r;
        if (px < 49) {
          float v = fmaxf(acc3[i][r] + c3v, 0.f);
          u16 h, l; split2(v, h, l);
          oph[oc * 49 + px] = h; opl[oc * 49 + px] = l;
        }
      }
    }
  }
}

// ---------------------------------------------------------------------------
// Group samples by expert — LDS atomics.
// ---------------------------------------------------------------------------
__global__ void group_kernel(const void* __restrict__ rmv,
                             int* __restrict__ counts, int* __restrict__ idxb)
{
  __shared__ int lcnt[8];
  __shared__ int isI32;
  const int t = threadIdx.x;
  if (t == 0) isI32 = 0;
  if (t < 8) lcnt[t] = 0;
  __syncthreads();
  unsigned long long v = ((const unsigned long long*)rmv)[t];
  if (v >= 8ull) isI32 = 1;
  __syncthreads();
  const int i32 = isI32;
  for (int b = t; b < BATCH; b += 1024) {
    int e = i32 ? ((const int*)rmv)[b] : (int)((const long long*)rmv)[b];
    int pos = atomicAdd(&lcnt[e], 1);
    idxb[e * BATCH + pos] = b;
  }
  __syncthreads();
  if (t < 8) counts[t] = lcnt[t];
}

// ---------------------------------------------------------------------------
// Fused MLP: gemm1 (MFMA hi/lo, K=3136, barrier-free: per-lane A-frags loaded
// DIRECT from global with cur/next rotation — no LDS staging) + tail 2..6
// in-block. Tiles of 32 samples: grid 512 (e = bid>>6, tl = bid&63), 512 thr
// = 8 waves (mh = w>>2: sample half, nt = w&3: out col tile).
// ---------------------------------------------------------------------------
__global__ __launch_bounds__(512, 4) void mlp_kernel(
    const u16* __restrict__ a3h, const u16* __restrict__ a3l,
    const int* __restrict__ counts, const int* __restrict__ idxb,
    const u16* __restrict__ W1s, const float* __restrict__ B1,
    const float* __restrict__ W2, const float* __restrict__ B2,
    const float* __restrict__ W3, const float* __restrict__ B3,
    const float* __restrict__ W4, const float* __restrict__ B4,
    const float* __restrict__ W5, const float* __restrict__ B5,
    const float* __restrict__ W6, const float* __restrict__ B6,
    float* __restrict__ out)
{
  __shared__ __align__(16) float Ht0[64 * 36];   // [c][r], r<32, stride 36
  __shared__ __align__(16) float Ht1[64 * 36];
  __shared__ __align__(16) float Wl[4096];
  __shared__ float bl[64];
  __shared__ float W6l[384];
  __shared__ float B6l[8];
  __shared__ int s_id[32];

  const int e  = blockIdx.x >> 6;
  const int tl = blockIdx.x & 63;
  const int cnt = counts[e];
  const int n0 = tl * 32;
  if (n0 >= cnt) return;
  const int m = min(32, cnt - n0);
  const int t = threadIdx.x;
  if (t < 32)  s_id[t] = idxb[e * BATCH + n0 + min(t, m - 1)];
  if (t < 384) W6l[t] = W6[e * 384 + t];
  if (t < 6)   B6l[t] = B6[e * 6 + t];
  __syncthreads();

  // ---- GEMM1: 32 samples x 64 outs, K = 3136 (98 chunks), no barriers ----
  const int lane = t & 63, w = t >> 6, q = lane >> 4, n = lane & 15;
  const int mh = w >> 2, nt = w & 3;
  const u16* Wb = W1s + (size_t)e * 200704;
  const size_t srow = (size_t)s_id[mh * 16 + n] * 3136;
  const int aoff = q * 8;
  const int obase = (nt * 16 + n) * 32 + q * 8;

  f32x4 acc = {};
  bf16x8 ahc = *(const bf16x8*)(a3h + srow + aoff);
  bf16x8 alc = *(const bf16x8*)(a3l + srow + aoff);
  bf16x8 bhc = *(const bf16x8*)(Wb + obase);
  bf16x8 boc = *(const bf16x8*)(Wb + 1605632 + obase);
  for (int ch = 0; ch < 98; ++ch) {
    const int chn = (ch < 97) ? ch + 1 : 97;
    bf16x8 ahn = *(const bf16x8*)(a3h + srow + chn * 32 + aoff);
    bf16x8 aln = *(const bf16x8*)(a3l + srow + chn * 32 + aoff);
    bf16x8 bhn = *(const bf16x8*)(Wb + chn * 2048 + obase);
    bf16x8 bon = *(const bf16x8*)(Wb + 1605632 + chn * 2048 + obase);
    acc = __builtin_amdgcn_mfma_f32_16x16x32_bf16(ahc, bhc, acc, 0, 0, 0);
    acc = __builtin_amdgcn_mfma_f32_16x16x32_bf16(ahc, boc, acc, 0, 0, 0);
    acc = __builtin_amdgcn_mfma_f32_16x16x32_bf16(alc, bhc, acc, 0, 0, 0);
    ahc = ahn; alc = aln; bhc = bhn; boc = bon;
  }

  // ---- H1 + bias + relu -> Ht0[c][r] -------------------------------------
  {
    const int c = nt * 16 + n;
    const float b1v = B1[e * 64 + c];
    #pragma unroll
    for (int rr = 0; rr < 4; ++rr)
      Ht0[c * 36 + mh * 16 + q * 4 + rr] = fmaxf(acc[rr] + b1v, 0.f);
  }

  // ---- tail layers 2..5 (scalar fp32, 512 thr: 1 row x 4 cols each) ------
  const int r0 = t >> 4, c0 = (t & 15) * 4;     // r0 0..31
  const float* Ws[4] = {W2, W3, W4, W5};
  const float* Bs[4] = {B2, B3, B4, B5};
  float* Hc = Ht0; float* Hn = Ht1;

  for (int L = 0; L < 4; ++L) {
    __syncthreads();
    const float* We = Ws[L] + (size_t)e * 4096;
    for (int i = t; i < 1024; i += 512)
      *(float4*)&Wl[i * 4] = *(const float4*)&We[i * 4];
    if (t < 64) bl[t] = Bs[L][e * 64 + t];
    __syncthreads();

    float acc4[4] = {};
    #pragma unroll 4
    for (int kk = 0; kk < 64; ++kk) {
      float a = Hc[kk * 36 + r0];
      float4 bb = *(const float4*)&Wl[kk * 64 + c0];
      acc4[0] += a * bb.x; acc4[1] += a * bb.y;
      acc4[2] += a * bb.z; acc4[3] += a * bb.w;
    }
    __syncthreads();
    #pragma unroll
    for (int j = 0; j < 4; ++j)
      Hn[(c0 + j) * 36 + r0] = fmaxf(acc4[j] + bl[c0 + j], 0.f);
    float* tmp = Hc; Hc = Hn; Hn = tmp;
  }
  __syncthreads();

  // ---- layer 6 + scatter --------------------------------------------------
  const int r = t & 31, aa = t >> 5;            // aa 0..15
  if (aa < 6) {
    float s = 0.f;
    for (int k = 0; k < 64; ++k)
      s += Hc[k * 36 + r] * W6l[k * 6 + aa];
    if (r < m) out[s_id[r] * 6 + aa] = s + B6l[aa];
  }
}

// ---------------------------------------------------------------------------
extern "C" void kernel_launch(void* const* d_in, const int* in_sizes, int n_in,
                              void* d_out, int out_size, void* d_ws, size_t ws_size,
                              hipStream_t stream) {
  const float* state = (const float*)d_in[0];
  const void*  rm    = d_in[1];
  const float* k1 = (const float*)d_in[2];
  const float* c1 = (const float*)d_in[3];
  const float* k2 = (const float*)d_in[4];
  const float* c2 = (const float*)d_in[5];
  const float* k3 = (const float*)d_in[6];
  const float* c3 = (const float*)d_in[7];
  const float* W1 = (const float*)d_in[8];
  const float* B1 = (const float*)d_in[9];
  const float* W2 = (const float*)d_in[10];
  const float* B2 = (const float*)d_in[11];
  const float* W3 = (const float*)d_in[12];
  const float* B3 = (const float*)d_in[13];
  const float* W4 = (const float*)d_in[14];
  const float* B4 = (const float*)d_in[15];
  const float* W5 = (const float*)d_in[16];
  const float* B5 = (const float*)d_in[17];
  const float* W6 = (const float*)d_in[18];
  const float* B6 = (const float*)d_in[19];

  // workspace layout (~32.5 MB; <= 66.7 MB proven-safe)
  char* ws = (char*)d_ws;
  u16* a3h    = (u16*)(ws);                    // 12,845,056
  u16* a3l    = (u16*)(ws + 12845056);         // 12,845,056 -> 25,690,112
  int* counts = (int*)(ws + 25690112);         //         32
  int* idxb   = (int*)(ws + 25690144);         //     65,536 -> 25,755,680
  u16* W1d    = (u16*)(ws + 25755680);         //     32,768 -> 25,788,448
  u16* W2d    = (u16*)(ws + 25788448);         //    131,072 -> 25,919,520
  u16* W3d    = (u16*)(ws + 25919520);         //    147,456 -> 26,066,976
  u16* W1s    = (u16*)(ws + 26066976);         //  6,422,528 -> 32,489,504

  wsplit_kernel<<<304, 256, 0, stream>>>(k1, k2, k3, W1d, W2d, W3d);
  w1split_kernel<<<784, 256, 0, stream>>>(W1, W1s);
  group_kernel<<<1, 1024, 0, stream>>>(rm, counts, idxb);

  conv_fused_kernel<<<2048, 512, 0, stream>>>(state, W1d, W2d, W3d,
                                              c1, c2, c3, a3h, a3l);

  mlp_kernel<<<512, 512, 0, stream>>>(a3h, a3l, counts, idxb, W1s, B1,
                                      W2, B2, W3, B3, W4, B4, W5, B5,
                                      W6, B6, (float*)d_out);
}

// Round 8
// 515.794 us; speedup vs baseline: 1.0310x; 1.0310x over previous
//
#include <hip/hip_runtime.h>

#define BATCH 2048

typedef unsigned short u16;
typedef __attribute__((ext_vector_type(8))) short bf16x8;  // 8 bf16 = 4 VGPR
typedef __attribute__((ext_vector_type(4))) float f32x4;   // MFMA 16x16 acc

static __device__ __forceinline__ float b2f(u16 h) {
  union { unsigned u; float f; } x; x.u = ((unsigned)h) << 16; return x.f;
}
static __device__ __forceinline__ u16 f2b(float f) {  // RNE fp32->bf16
  union { float f; unsigned u; } x; x.f = f;
  return (u16)((x.u + 0x7fffu + ((x.u >> 16) & 1u)) >> 16);
}
static __device__ __forceinline__ void split2(float v, u16& h, u16& l) {
  h = f2b(v); l = f2b(v - b2f(h));
}
// 8 bf16 from LDS, 8B-aligned (2x ds_read_b64)
static __device__ __forceinline__ bf16x8 ld8u(const u16* p, int idx) {
  union { bf16x8 v; ushort4 u[2]; } x;
  x.u[0] = *(const ushort4*)(p + idx);
  x.u[1] = *(const ushort4*)(p + idx + 4);
  return x.v;
}
// 8 bf16 from LDS, 4B-aligned (4x ds_read_b32) — for odd-word-stride tiles
static __device__ __forceinline__ bf16x8 ld8w(const u16* p, int idx) {
  union { bf16x8 v; ushort2 u[4]; } x;
  x.u[0] = *(const ushort2*)(p + idx);
  x.u[1] = *(const ushort2*)(p + idx + 2);
  x.u[2] = *(const ushort2*)(p + idx + 4);
  x.u[3] = *(const ushort2*)(p + idx + 6);
  return x.v;
}

// ---------------------------------------------------------------------------
// Pre-split conv weights into direct-conv position-major layouts (hi plane
// then lo plane):
//   W1d [8 ky][32 oc][32 k]  k = kx*3+c for k<24, zeros k>=24  (8192 + 8192)
//   W2d [16 pos][64 oc][32 cc]                                (32768 + 32768)
//   W3d [9 pos][2 kc][64 oc][32 j]  cc = kc*32+j              (36864 + 36864)
// ---------------------------------------------------------------------------
__global__ void wsplit_kernel(const float* __restrict__ k1,
                              const float* __restrict__ k2,
                              const float* __restrict__ k3,
                              u16* __restrict__ W1d, u16* __restrict__ W2d,
                              u16* __restrict__ W3d)
{
  int id = blockIdx.x * 256 + threadIdx.x;   // 0..77823
  float v; u16 *dh, *dl;
  if (id < 8192) {
    int ky = id >> 10, oc = (id >> 5) & 31, kk = id & 31;
    if (kk < 24) {
      int kx = kk / 3, c = kk - kx * 3;
      v = k1[oc * 192 + c * 64 + ky * 8 + kx];
    } else v = 0.f;
    dh = W1d + id; dl = W1d + 8192 + id;
  } else if (id < 40960) {
    int i = id - 8192;
    int pos = i >> 11, oc = (i >> 5) & 63, cc = i & 31;
    int ky = pos >> 2, kx = pos & 3;
    v = k2[oc * 512 + cc * 16 + ky * 4 + kx];
    dh = W2d + i; dl = W2d + 32768 + i;
  } else {
    int i = id - 40960;                      // ((pos*2+kc)*64+oc)*32 + j
    int j = i & 31, oc = (i >> 5) & 63, kc = (i >> 11) & 1, pos = i >> 12;
    int ky = pos / 3, kx = pos - ky * 3;
    v = k3[oc * 576 + (kc * 32 + j) * 9 + ky * 3 + kx];
    dh = W3d + i; dl = W3d + 36864 + i;
  }
  u16 h, l; split2(v, h, l); *dh = h; *dl = l;
}

// ---------------------------------------------------------------------------
// Pre-split W1 [8][3136][64] fp32 -> W1s hi/lo bf16, B-frag layout
// [e][chunk][c(64)][kk(32)]. One block per (e,chunk) = 784 blocks x 256 thr.
// Coalesced reads (64B groups) and 16B-contiguous writes.
// ---------------------------------------------------------------------------
__global__ void w1split_kernel(const float* __restrict__ W1,
                               u16* __restrict__ W1s)
{
  const int bc = blockIdx.x;                 // e*98 + chunk
  const int e = bc / 98, chunk = bc - e * 98;
  const int t = threadIdx.x;
  const float* in = W1 + (size_t)e * 200704 + chunk * 2048;
  const int c = t >> 2, kk0 = (t & 3) * 8;
  u16 h[8], l[8];
  #pragma unroll
  for (int j = 0; j < 8; ++j) {
    float v = in[(kk0 + j) * 64 + c];
    split2(v, h[j], l[j]);
  }
  ushort4 h0; h0.x = h[0]; h0.y = h[1]; h0.z = h[2]; h0.w = h[3];
  ushort4 h1; h1.x = h[4]; h1.y = h[5]; h1.z = h[6]; h1.w = h[7];
  ushort4 l0; l0.x = l[0]; l0.y = l[1]; l0.z = l[2]; l0.w = l[3];
  ushort4 l1; l1.x = l[4]; l1.y = l[5]; l1.z = l[6]; l1.w = l[7];
  size_t d = (size_t)e * 200704 + chunk * 2048 + t * 8;   // = c*32 + kk0
  *(ushort4*)(W1s + d)     = h0;
  *(ushort4*)(W1s + d + 4) = h1;
  *(ushort4*)(W1s + 1605632 + d)     = l0;
  *(ushort4*)(W1s + 1605632 + d + 4) = l1;
}

// ---------------------------------------------------------------------------
// Fused conv1+conv2+conv3, one block per image, 512 thr = 8 waves.
// Bank-conflict-tuned LDS layouts:
//   a1 [r1(px)][34] with parity-interleaved rows r1 = (y&1)*200+(y>>1)*20+
//      (x&1)*10+(x>>1): conv2's s2 accesses become stride-1 rows (17 words,
//      odd -> ~2-way banks, was 8-way). Reads via 4x b32 (4B-aligned).
//   a2 [81][74]: stride 37 words (== 5 mod 32, <=2-way family; was 8-way).
// conv1: T14 async staging — next band's state loads issued into registers
// before compute, LDS-written after the barrier (HBM latency hidden).
// ---------------------------------------------------------------------------
__global__ __launch_bounds__(512, 4) void conv_fused_kernel(
    const float* __restrict__ state, const u16* __restrict__ W1d,
    const u16* __restrict__ W2d, const u16* __restrict__ W3d,
    const float* __restrict__ c1, const float* __restrict__ c2,
    const float* __restrict__ c3, u16* __restrict__ a3h,
    u16* __restrict__ a3l)
{
  __shared__ __align__(16) u16 A1h[13600], A1l[13600];  // [400 r1][34]
  __shared__ __align__(16) u16 SHa[5994], SHb[5994];    // il [20][252] / a2 [81][74]

  const int b = blockIdx.x, t = threadIdx.x;
  const int lane = t & 63, w = t >> 6, q = lane >> 4, n = lane & 15;

  // Zero the il tail: conv1's zero-weight pad lanes read past the il band
  // (up to SHa[5047]); stale Inf/NaN bf16 would make 0*x = NaN.
  for (int i = t; i < 792; i += 512) { SHa[5040 + i] = 0; SHb[5040 + i] = 0; }

  // ================= conv1: 84x84x3 -> 20x20x32, 8x8 s4, 5 bands =========
  const int nT1 = (w < 2) ? 2 : 1;
  int pt1[2], ot1[2];
  if (w < 2) { pt1[0] = 0; ot1[0] = w; pt1[1] = 4; ot1[1] = w; }
  else       { pt1[0] = 1 + ((w - 2) >> 1); ot1[0] = (w - 2) & 1;
               pt1[1] = pt1[0]; ot1[1] = ot1[0]; }

  int aoff1[2];
  #pragma unroll
  for (int i = 0; i < 2; ++i) {
    int px = pt1[i] * 16 + n;                 // <= 79
    int py = (px * 205) >> 12, pxx = px - py * 20;
    aoff1[i] = (py * 4) * 252 + pxx * 12 + q * 8;
  }
  float c1v[2];
  #pragma unroll
  for (int j = 0; j < 2; ++j) c1v[j] = c1[ot1[j] * 16 + n];
  const int ob1 = (ot1[0] * 16 + n) * 32 + q * 8;   // + ky*1024

  // async-stage registers: band = 1260 float4; threads cover 3 passes
  const float4* spB = (const float4*)(state + (size_t)b * 21168);
  float4 rb0, rb1, rb2;
  rb0 = spB[t];
  if (t < 748) rb1 = spB[t + 512];
  if (t < 236) rb2 = spB[t + 1024];

  for (int by = 0; by < 5; ++by) {
    __syncthreads();                          // all waves done reading il
    // write il from regs (vmcnt waits folded here)
    {
      float4 v = rb0;
      u16 h0,l0,h1,l1,h2,l2,h3,l3;
      split2(v.x,h0,l0); split2(v.y,h1,l1); split2(v.z,h2,l2); split2(v.w,h3,l3);
      ushort4 hh; hh.x=h0; hh.y=h1; hh.z=h2; hh.w=h3;
      ushort4 ll; ll.x=l0; ll.y=l1; ll.z=l2; ll.w=l3;
      *(ushort4*)&SHa[t * 4] = hh; *(ushort4*)&SHb[t * 4] = ll;
    }
    if (t < 748) {
      float4 v = rb1;
      u16 h0,l0,h1,l1,h2,l2,h3,l3;
      split2(v.x,h0,l0); split2(v.y,h1,l1); split2(v.z,h2,l2); split2(v.w,h3,l3);
      ushort4 hh; hh.x=h0; hh.y=h1; hh.z=h2; hh.w=h3;
      ushort4 ll; ll.x=l0; ll.y=l1; ll.z=l2; ll.w=l3;
      *(ushort4*)&SHa[(t + 512) * 4] = hh; *(ushort4*)&SHb[(t + 512) * 4] = ll;
    }
    if (t < 236) {
      float4 v = rb2;
      u16 h0,l0,h1,l1,h2,l2,h3,l3;
      split2(v.x,h0,l0); split2(v.y,h1,l1); split2(v.z,h2,l2); split2(v.w,h3,l3);
      ushort4 hh; hh.x=h0; hh.y=h1; hh.z=h2; hh.w=h3;
      ushort4 ll; ll.x=l0; ll.y=l1; ll.z=l2; ll.w=l3;
      *(ushort4*)&SHa[(t + 1024) * 4] = hh; *(ushort4*)&SHb[(t + 1024) * 4] = ll;
    }
    if (by < 4) {                             // issue next band (overlaps compute)
      const float4* spN = spB + (by + 1) * 1008;
      rb0 = spN[t];
      if (t < 748) rb1 = spN[t + 512];
      if (t < 236) rb2 = spN[t + 1024];
    }
    __syncthreads();                          // il ready

    f32x4 acc1[2] = {};
    bf16x8 bhc = *(const bf16x8*)(W1d + ob1);
    bf16x8 boc = *(const bf16x8*)(W1d + 8192 + ob1);
    for (int ky = 0; ky < 8; ++ky) {
      const int kyn = (ky < 7) ? ky + 1 : 7;
      bf16x8 bhn = *(const bf16x8*)(W1d + kyn * 1024 + ob1);
      bf16x8 bon = *(const bf16x8*)(W1d + 8192 + kyn * 1024 + ob1);
      #pragma unroll
      for (int i = 0; i < 2; ++i) if (i < nT1) {
        bf16x8 ah = ld8u(SHa, aoff1[i] + ky * 252);
        bf16x8 al = ld8u(SHb, aoff1[i] + ky * 252);
        acc1[i] = __builtin_amdgcn_mfma_f32_16x16x32_bf16(ah, bhc, acc1[i], 0, 0, 0);
        acc1[i] = __builtin_amdgcn_mfma_f32_16x16x32_bf16(ah, boc, acc1[i], 0, 0, 0);
        acc1[i] = __builtin_amdgcn_mfma_f32_16x16x32_bf16(al, bhc, acc1[i], 0, 0, 0);
      }
      bhc = bhn; boc = bon;
    }
    // epilogue: bias+relu, split, store a1 [r1][34] (parity-interleaved)
    #pragma unroll
    for (int i = 0; i < 2; ++i) if (i < nT1) {
      int oc = ot1[i] * 16 + n;
      #pragma unroll
      for (int r = 0; r < 4; ++r) {
        int px = by * 80 + pt1[i] * 16 + q * 4 + r;
        int y = (px * 205) >> 12, x = px - y * 20;
        int r1 = (y & 1) * 200 + (y >> 1) * 20 + (x & 1) * 10 + (x >> 1);
        float v = fmaxf(acc1[i][r] + c1v[i], 0.f);
        u16 h, l; split2(v, h, l);
        A1h[r1 * 34 + oc] = h; A1l[r1 * 34 + oc] = l;
      }
    }
  }
  __syncthreads();

  // ================= conv2: 20x20x32 -> 9x9x64, 4x4 s2 ===================
  {
    const int ot2 = w & 3, pg2 = (w >> 2) * 3;
    int aoff2[3];
    #pragma unroll
    for (int i = 0; i < 3; ++i) {
      int o = (pg2 + i) * 16 + n; if (o > 80) o = 80;
      int oy = (o * 7282) >> 16, ox = o - oy * 9;
      aoff2[i] = (oy * 20 + ox) * 34 + q * 8;
    }
    const float c2v = c2[ot2 * 16 + n];
    const int ob2 = (ot2 * 16 + n) * 32 + q * 8;

    f32x4 acc2[3] = {};
    bf16x8 bhc = *(const bf16x8*)(W2d + ob2);
    bf16x8 boc = *(const bf16x8*)(W2d + 32768 + ob2);
    for (int pos = 0; pos < 16; ++pos) {
      const int posn = (pos < 15) ? pos + 1 : 15;
      bf16x8 bhn = *(const bf16x8*)(W2d + posn * 2048 + ob2);
      bf16x8 bon = *(const bf16x8*)(W2d + 32768 + posn * 2048 + ob2);
      const int ky = pos >> 2, kx = pos & 3;
      const int o2 = ((ky & 1) * 200 + (ky >> 1) * 20 +
                      (kx & 1) * 10 + (kx >> 1)) * 34;
      #pragma unroll
      for (int i = 0; i < 3; ++i) {
        bf16x8 ah = ld8w(A1h, aoff2[i] + o2);
        bf16x8 al = ld8w(A1l, aoff2[i] + o2);
        acc2[i] = __builtin_amdgcn_mfma_f32_16x16x32_bf16(ah, bhc, acc2[i], 0, 0, 0);
        acc2[i] = __builtin_amdgcn_mfma_f32_16x16x32_bf16(ah, boc, acc2[i], 0, 0, 0);
        acc2[i] = __builtin_amdgcn_mfma_f32_16x16x32_bf16(al, bhc, acc2[i], 0, 0, 0);
      }
      bhc = bhn; boc = bon;
    }
    // epilogue: a2 [81][74] into SH region (il is dead)
    #pragma unroll
    for (int i = 0; i < 3; ++i) {
      int oc = ot2 * 16 + n;
      #pragma unroll
      for (int r = 0; r < 4; ++r) {
        int px = (pg2 + i) * 16 + q * 4 + r;
        if (px < 81) {
          float v = fmaxf(acc2[i][r] + c2v, 0.f);
          u16 h, l; split2(v, h, l);
          SHa[px * 74 + oc] = h; SHb[px * 74 + oc] = l;
        }
      }
    }
  }
  __syncthreads();

  // ================= conv3: 9x9x64 -> 7x7x64, 3x3 s1 =====================
  {
    const int ot3 = w & 3, pg3 = (w >> 2) * 2;
    int aoff3[2];
    #pragma unroll
    for (int i = 0; i < 2; ++i) {
      int px = (pg3 + i) * 16 + n; if (px > 48) px = 48;
      int py = (px * 74) >> 9, pxx = px - py * 7;
      aoff3[i] = (py * 9 + pxx) * 74 + q * 8;
    }
    const float c3v = c3[ot3 * 16 + n];
    const int ob3 = (ot3 * 16 + n) * 32 + q * 8;

    f32x4 acc3[2] = {};
    bf16x8 bhc = *(const bf16x8*)(W3d + ob3);
    bf16x8 boc = *(const bf16x8*)(W3d + 36864 + ob3);
    for (int pk = 0; pk < 18; ++pk) {           // pk = pos*2 + kc
      const int pkn = (pk < 17) ? pk + 1 : 17;
      bf16x8 bhn = *(const bf16x8*)(W3d + pkn * 2048 + ob3);
      bf16x8 bon = *(const bf16x8*)(W3d + 36864 + pkn * 2048 + ob3);
      const int pos = pk >> 1, kc = pk & 1;
      const int ky = pos / 3, kx = pos - ky * 3;
      const int o3 = (ky * 9 + kx) * 74 + kc * 32;
      #pragma unroll
      for (int i = 0; i < 2; ++i) {
        bf16x8 ah = ld8w(SHa, aoff3[i] + o3);
        bf16x8 al = ld8w(SHb, aoff3[i] + o3);
        acc3[i] = __builtin_amdgcn_mfma_f32_16x16x32_bf16(ah, bhc, acc3[i], 0, 0, 0);
        acc3[i] = __builtin_amdgcn_mfma_f32_16x16x32_bf16(ah, boc, acc3[i], 0, 0, 0);
        acc3[i] = __builtin_amdgcn_mfma_f32_16x16x32_bf16(al, bhc, acc3[i], 0, 0, 0);
      }
      bhc = bhn; boc = bon;
    }
    u16* oph = a3h + (size_t)b * 3136;
    u16* opl = a3l + (size_t)b * 3136;
    #pragma unroll
    for (int i = 0; i < 2; ++i) {
      int oc = ot3 * 16 + n;
      #pragma unroll
      for (int r = 0; r < 4; ++r) {
        int px = (pg3 + i) * 16 + q * 4 + r;
        if (px < 49) {
          float v = fmaxf(acc3[i][r] + c3v, 0.f);
          u16 h, l; split2(v, h, l);
          oph[oc * 49 + px] = h; opl[oc * 49 + px] = l;
        }
      }
    }
  }
}

// ---------------------------------------------------------------------------
// Group samples by expert — LDS atomics.
// ---------------------------------------------------------------------------
__global__ void group_kernel(const void* __restrict__ rmv,
                             int* __restrict__ counts, int* __restrict__ idxb)
{
  __shared__ int lcnt[8];
  __shared__ int isI32;
  const int t = threadIdx.x;
  if (t == 0) isI32 = 0;
  if (t < 8) lcnt[t] = 0;
  __syncthreads();
  unsigned long long v = ((const unsigned long long*)rmv)[t];
  if (v >= 8ull) isI32 = 1;
  __syncthreads();
  const int i32 = isI32;
  for (int b = t; b < BATCH; b += 1024) {
    int e = i32 ? ((const int*)rmv)[b] : (int)((const long long*)rmv)[b];
    int pos = atomicAdd(&lcnt[e], 1);
    idxb[e * BATCH + pos] = b;
  }
  __syncthreads();
  if (t < 8) counts[t] = lcnt[t];
}

// ---------------------------------------------------------------------------
// Fused MLP: gemm1 (MFMA hi/lo, K=3136, barrier-free: per-lane A-frags loaded
// DIRECT from global with cur/next rotation) + tail 2..6 in-block.
// Tiles of 32 samples: grid 512 (e = bid>>6, tl = bid&63), 512 thr = 8 waves.
// ---------------------------------------------------------------------------
__global__ __launch_bounds__(512, 4) void mlp_kernel(
    const u16* __restrict__ a3h, const u16* __restrict__ a3l,
    const int* __restrict__ counts, const int* __restrict__ idxb,
    const u16* __restrict__ W1s, const float* __restrict__ B1,
    const float* __restrict__ W2, const float* __restrict__ B2,
    const float* __restrict__ W3, const float* __restrict__ B3,
    const float* __restrict__ W4, const float* __restrict__ B4,
    const float* __restrict__ W5, const float* __restrict__ B5,
    const float* __restrict__ W6, const float* __restrict__ B6,
    float* __restrict__ out)
{
  __shared__ __align__(16) float Ht0[64 * 36];   // [c][r], r<32, stride 36
  __shared__ __align__(16) float Ht1[64 * 36];
  __shared__ __align__(16) float Wl[4096];
  __shared__ float bl[64];
  __shared__ float W6l[384];
  __shared__ float B6l[8];
  __shared__ int s_id[32];

  const int e  = blockIdx.x >> 6;
  const int tl = blockIdx.x & 63;
  const int cnt = counts[e];
  const int n0 = tl * 32;
  if (n0 >= cnt) return;
  const int m = min(32, cnt - n0);
  const int t = threadIdx.x;
  if (t < 32)  s_id[t] = idxb[e * BATCH + n0 + min(t, m - 1)];
  if (t < 384) W6l[t] = W6[e * 384 + t];
  if (t < 6)   B6l[t] = B6[e * 6 + t];
  __syncthreads();

  // ---- GEMM1: 32 samples x 64 outs, K = 3136 (98 chunks), no barriers ----
  const int lane = t & 63, w = t >> 6, q = lane >> 4, n = lane & 15;
  const int mh = w >> 2, nt = w & 3;
  const u16* Wb = W1s + (size_t)e * 200704;
  const size_t srow = (size_t)s_id[mh * 16 + n] * 3136;
  const int aoff = q * 8;
  const int obase = (nt * 16 + n) * 32 + q * 8;

  f32x4 acc = {};
  bf16x8 ahc = *(const bf16x8*)(a3h + srow + aoff);
  bf16x8 alc = *(const bf16x8*)(a3l + srow + aoff);
  bf16x8 bhc = *(const bf16x8*)(Wb + obase);
  bf16x8 boc = *(const bf16x8*)(Wb + 1605632 + obase);
  for (int ch = 0; ch < 98; ++ch) {
    const int chn = (ch < 97) ? ch + 1 : 97;
    bf16x8 ahn = *(const bf16x8*)(a3h + srow + chn * 32 + aoff);
    bf16x8 aln = *(const bf16x8*)(a3l + srow + chn * 32 + aoff);
    bf16x8 bhn = *(const bf16x8*)(Wb + chn * 2048 + obase);
    bf16x8 bon = *(const bf16x8*)(Wb + 1605632 + chn * 2048 + obase);
    acc = __builtin_amdgcn_mfma_f32_16x16x32_bf16(ahc, bhc, acc, 0, 0, 0);
    acc = __builtin_amdgcn_mfma_f32_16x16x32_bf16(ahc, boc, acc, 0, 0, 0);
    acc = __builtin_amdgcn_mfma_f32_16x16x32_bf16(alc, bhc, acc, 0, 0, 0);
    ahc = ahn; alc = aln; bhc = bhn; boc = bon;
  }

  // ---- H1 + bias + relu -> Ht0[c][r] -------------------------------------
  {
    const int c = nt * 16 + n;
    const float b1v = B1[e * 64 + c];
    #pragma unroll
    for (int rr = 0; rr < 4; ++rr)
      Ht0[c * 36 + mh * 16 + q * 4 + rr] = fmaxf(acc[rr] + b1v, 0.f);
  }

  // ---- tail layers 2..5 (scalar fp32, 512 thr: 1 row x 4 cols each) ------
  const int r0 = t >> 4, c0 = (t & 15) * 4;     // r0 0..31
  const float* Ws[4] = {W2, W3, W4, W5};
  const float* Bs[4] = {B2, B3, B4, B5};
  float* Hc = Ht0; float* Hn = Ht1;

  for (int L = 0; L < 4; ++L) {
    __syncthreads();
    const float* We = Ws[L] + (size_t)e * 4096;
    for (int i = t; i < 1024; i += 512)
      *(float4*)&Wl[i * 4] = *(const float4*)&We[i * 4];
    if (t < 64) bl[t] = Bs[L][e * 64 + t];
    __syncthreads();

    float acc4[4] = {};
    #pragma unroll 4
    for (int kk = 0; kk < 64; ++kk) {
      float a = Hc[kk * 36 + r0];
      float4 bb = *(const float4*)&Wl[kk * 64 + c0];
      acc4[0] += a * bb.x; acc4[1] += a * bb.y;
      acc4[2] += a * bb.z; acc4[3] += a * bb.w;
    }
    __syncthreads();
    #pragma unroll
    for (int j = 0; j < 4; ++j)
      Hn[(c0 + j) * 36 + r0] = fmaxf(acc4[j] + bl[c0 + j], 0.f);
    float* tmp = Hc; Hc = Hn; Hn = tmp;
  }
  __syncthreads();

  // ---- layer 6 + scatter --------------------------------------------------
  const int r = t & 31, aa = t >> 5;            // aa 0..15
  if (aa < 6) {
    float s = 0.f;
    for (int k = 0; k < 64; ++k)
      s += Hc[k * 36 + r] * W6l[k * 6 + aa];
    if (r < m) out[s_id[r] * 6 + aa] = s + B6l[aa];
  }
}

// ---------------------------------------------------------------------------
extern "C" void kernel_launch(void* const* d_in, const int* in_sizes, int n_in,
                              void* d_out, int out_size, void* d_ws, size_t ws_size,
                              hipStream_t stream) {
  const float* state = (const float*)d_in[0];
  const void*  rm    = d_in[1];
  const float* k1 = (const float*)d_in[2];
  const float* c1 = (const float*)d_in[3];
  const float* k2 = (const float*)d_in[4];
  const float* c2 = (const float*)d_in[5];
  const float* k3 = (const float*)d_in[6];
  const float* c3 = (const float*)d_in[7];
  const float* W1 = (const float*)d_in[8];
  const float* B1 = (const float*)d_in[9];
  const float* W2 = (const float*)d_in[10];
  const float* B2 = (const float*)d_in[11];
  const float* W3 = (const float*)d_in[12];
  const float* B3 = (const float*)d_in[13];
  const float* W4 = (const float*)d_in[14];
  const float* B4 = (const float*)d_in[15];
  const float* W5 = (const float*)d_in[16];
  const float* B5 = (const float*)d_in[17];
  const float* W6 = (const float*)d_in[18];
  const float* B6 = (const float*)d_in[19];

  // workspace layout (~32.5 MB; <= 66.7 MB proven-safe)
  char* ws = (char*)d_ws;
  u16* a3h    = (u16*)(ws);                    // 12,845,056
  u16* a3l    = (u16*)(ws + 12845056);         // 12,845,056 -> 25,690,112
  int* counts = (int*)(ws + 25690112);         //         32
  int* idxb   = (int*)(ws + 25690144);         //     65,536 -> 25,755,680
  u16* W1d    = (u16*)(ws + 25755680);         //     32,768 -> 25,788,448
  u16* W2d    = (u16*)(ws + 25788448);         //    131,072 -> 25,919,520
  u16* W3d    = (u16*)(ws + 25919520);         //    147,456 -> 26,066,976
  u16* W1s    = (u16*)(ws + 26066976);         //  6,422,528 -> 32,489,504

  wsplit_kernel<<<304, 256, 0, stream>>>(k1, k2, k3, W1d, W2d, W3d);
  w1split_kernel<<<784, 256, 0, stream>>>(W1, W1s);
  group_kernel<<<1, 1024, 0, stream>>>(rm, counts, idxb);

  conv_fused_kernel<<<2048, 512, 0, stream>>>(state, W1d, W2d, W3d,
                                              c1, c2, c3, a3h, a3l);

  mlp_kernel<<<512, 512, 0, stream>>>(a3h, a3l, counts, idxb, W1s, B1,
                                      W2, B2, W3, B3, W4, B4, W5, B5,
                                      W6, B6, (float*)d_out);
}